// Round 19
// baseline (79.403 us; speedup 1.0000x reference)
//
#include <hip/hip_runtime.h>
#include <hip/hip_fp16.h>
#include <math.h>

#define EPS 1e-7f
#define PROJ_EPS 1e-5f
#define MAXNORM (1.0f - PROJ_EPS)
#define D_DIM 128
#define CAP 48          // bucket capacity; deg ~ Binom(640k,1/50k), P(deg>48) ~ 1e-20
#define PSHIFT 7        // partition = row >> 7  (128 rows/partition)
#define NPART 392       // 50000>>7 = 390 max -> 391 used, pad to 392
#define PCAP 2048       // edges per partition: mean 1638, sigma 40 -> 10 sigma margin
#define CHUNK 4096      // edges per part block
#define NCONV 32        // blocks converting rels fp32 -> fp16
#define ATS 136         // atile k-stride (halfs)
#define WTS 136         // wtile k-stride (halfs)
#define PRE0_SMEM (64 * 132 * 4)
#define MAIN_SMEM (64 * ATS * 2 + 128 * WTS * 2 + 256)   // 52.5 KB: gemm arena >= part arena

typedef _Float16 f16;
typedef __attribute__((ext_vector_type(4))) _Float16 f16x4;
typedef __attribute__((ext_vector_type(8))) _Float16 f16x8;
typedef __attribute__((ext_vector_type(4))) float f32x4;

// ---------------- helpers ----------------
__device__ inline float wred(float v) {
    #pragma unroll
    for (int o = 32; o; o >>= 1) v += __shfl_xor(v, o, 64);
    return v;
}
__device__ inline float gred(float v) {
    v += __shfl_xor(v, 1, 64);
    v += __shfl_xor(v, 2, 64);
    v += __shfl_xor(v, 4, 64);
    v += __shfl_xor(v, 8, 64);
    return v;
}
__device__ inline void gred4(float& a, float& b, float& c, float& d) {
    a += __shfl_xor(a, 1, 64);  b += __shfl_xor(b, 1, 64);
    c += __shfl_xor(c, 1, 64);  d += __shfl_xor(d, 1, 64);
    a += __shfl_xor(a, 2, 64);  b += __shfl_xor(b, 2, 64);
    c += __shfl_xor(c, 2, 64);  d += __shfl_xor(d, 2, 64);
    a += __shfl_xor(a, 4, 64);  b += __shfl_xor(b, 4, 64);
    c += __shfl_xor(c, 4, 64);  d += __shfl_xor(d, 4, 64);
    a += __shfl_xor(a, 8, 64);  b += __shfl_xor(b, 8, 64);
    c += __shfl_xor(c, 8, 64);  d += __shfl_xor(d, 8, 64);
}
__device__ inline __half2 bc_h2(unsigned int u) { return *(__half2*)&u; }
__device__ inline unsigned int bc_u32(__half2 h) { return *(unsigned int*)&h; }

typedef _Float16 h2v __attribute__((ext_vector_type(2)));
__device__ inline h2v as_h2v(unsigned int u) { union { unsigned int u; h2v h; } c; c.u = u; return c.h; }

__device__ inline float dot8d(uint4 a, uint4 v) {
#if __has_builtin(__builtin_amdgcn_fdot2)
    float s = __builtin_amdgcn_fdot2(as_h2v(a.x), as_h2v(v.x), 0.f, false);
    s = __builtin_amdgcn_fdot2(as_h2v(a.y), as_h2v(v.y), s, false);
    s = __builtin_amdgcn_fdot2(as_h2v(a.z), as_h2v(v.z), s, false);
    s = __builtin_amdgcn_fdot2(as_h2v(a.w), as_h2v(v.w), s, false);
    return s;
#else
    __half2 t = __hmul2(bc_h2(a.x), bc_h2(v.x));
    t = __hfma2(bc_h2(a.y), bc_h2(v.y), t);
    t = __hfma2(bc_h2(a.z), bc_h2(v.z), t);
    t = __hfma2(bc_h2(a.w), bc_h2(v.w), t);
    return __low2float(t) + __high2float(t);
#endif
}
__device__ inline void acc8h(__half2* A, float w, uint4 v) {
    __half2 w2 = __float2half2_rn(w);
    A[0] = __hfma2(w2, bc_h2(v.x), A[0]);
    A[1] = __hfma2(w2, bc_h2(v.y), A[1]);
    A[2] = __hfma2(w2, bc_h2(v.z), A[2]);
    A[3] = __hfma2(w2, bc_h2(v.w), A[3]);
}
__device__ inline void add8h(__half2* A, uint4 v) {
    A[0] = __hadd2(A[0], bc_h2(v.x));
    A[1] = __hadd2(A[1], bc_h2(v.y));
    A[2] = __hadd2(A[2], bc_h2(v.z));
    A[3] = __hadd2(A[3], bc_h2(v.w));
}

// ---------------- K0: k_pre0 = {bias + cursors-zero | W-transpose->fp16} ----------------
__global__ __launch_bounds__(256) void k_pre0(
    const float* __restrict__ W, f16* __restrict__ Wt_h,
    const float* __restrict__ bias, float* __restrict__ bws,
    int* __restrict__ cursors) {
    __shared__ alignas(16) unsigned char smem[PRE0_SMEM];
    int tid = threadIdx.x;

    if (blockIdx.x == 0) {
        for (int i = tid; i < 2 * NPART; i += 256) cursors[i] = 0;
        if (tid < 64) {
            int l = tid;
            float2 bv = ((const float2*)bias)[l];
            float bn = fmaxf(sqrtf(wred(bv.x * bv.x + bv.y * bv.y)), EPS);
            float gb = tanhf(fminf(bn, 15.f)) / bn;
            float bx = gb * bv.x, by = gb * bv.y;
            float nb = fmaxf(sqrtf(wred(bx * bx + by * by)), EPS);
            float pb = fminf(1.f, MAXNORM / nb);
            bx *= pb; by *= pb;
            ((float2*)bws)[l] = make_float2(bx, by);
            float v2 = wred(bx * bx + by * by);
            if (l == 0) bws[128] = v2;
        }
        return;
    }

    // ---- W [k][c] fp32 -> Wt_h [c][k] fp16 (two 64-row passes through LDS) ----
    float* lts = (float*)smem;          // [64][132]
    unsigned int* wt_u = (unsigned int*)Wt_h;
    for (int pass = 0; pass < 2; pass++) {
        #pragma unroll
        for (int i = 0; i < 8; i++) {
            int flat = (tid + i * 256) * 4;
            int kr = flat >> 7, cc = flat & 127;
            float4 x = *(const float4*)(W + (size_t)(pass * 64 + kr) * D_DIM + cc);
            *(float4*)&lts[kr * 132 + cc] = x;
        }
        __syncthreads();
        #pragma unroll
        for (int i = 0; i < 16; i++) {
            int flat2 = tid + i * 256;
            int c = flat2 >> 5, kp = flat2 & 31;
            float lo = lts[(2 * kp) * 132 + c];
            float hi = lts[(2 * kp + 1) * 132 + c];
            wt_u[c * 64 + pass * 32 + kp] = bc_u32(__float22half2_rn(make_float2(lo, hi)));
        }
        __syncthreads();
    }
}

// ---------------- K1: k_main = {MFMA logmap-GEMM | rels->fp16 | partition} ----------------
__global__ __launch_bounds__(256) void k_main(
    const float* __restrict__ ents, const f16* __restrict__ Wt_h,
    __half* __restrict__ hh,
    const int* __restrict__ er, const int* __restrict__ ec,
    const int* __restrict__ rr, const int* __restrict__ rv,
    int* __restrict__ part_e, int* __restrict__ part_r,
    int* __restrict__ cursors,
    const float* __restrict__ rels, f16* __restrict__ rels_h, int relsN4,
    int N, int E, int nGemm, int nChunk) {
    __shared__ alignas(16) unsigned char smem[MAIN_SMEM];
    int tid = threadIdx.x;
    int bid = blockIdx.x;

    if (bid < nGemm) {
        f16* atile = (f16*)smem;
        f16* wtile = (f16*)(smem + 64 * ATS * 2);
        float* fac = (float*)(smem + 64 * ATS * 2 + 128 * WTS * 2);
        int lane = tid & 63;
        int wv = tid >> 6;
        int r0 = bid * 64;

        #pragma unroll
        for (int i = 0; i < 8; i++) {
            int flat = (tid + i * 256) * 4;
            int rr2 = flat >> 7, cc = flat & 127;
            float4 x = make_float4(0.f, 0.f, 0.f, 0.f);
            if (r0 + rr2 < N) x = *(const float4*)(ents + (size_t)(r0 + rr2) * D_DIM + cc);
            f16x4 v4 = {(f16)x.x, (f16)x.y, (f16)x.z, (f16)x.w};
            *(f16x4*)&atile[rr2 * ATS + cc] = v4;
            float s = x.x * x.x + x.y * x.y + x.z * x.z + x.w * x.w;
            s += __shfl_xor(s, 1, 64);
            s += __shfl_xor(s, 2, 64);
            s += __shfl_xor(s, 4, 64);
            s += __shfl_xor(s, 8, 64);
            s += __shfl_xor(s, 16, 64);
            if ((lane & 31) == 0) fac[rr2] = s;
        }
        #pragma unroll
        for (int i = 0; i < 8; i++) {
            int flat4 = tid + i * 256;
            int c = flat4 >> 4, off = (flat4 & 15) * 8;
            uint4 u = ((const uint4*)Wt_h)[flat4];
            *(uint4*)&wtile[c * WTS + off] = u;
        }
        __syncthreads();

        if (tid < 64) {
            float n = sqrtf(fac[tid]);
            float ncl = fminf(fmaxf(n, EPS), MAXNORM);
            float at = 0.5f * logf((1.f + ncl) / (1.f - ncl));
            fac[tid] = at / fmaxf(n, EPS);
        }
        __syncthreads();

        int l15 = lane & 15, kseg = lane >> 4;
        int arow = wv * 16 + l15;

        f32x4 acc[8];
        #pragma unroll
        for (int ct = 0; ct < 8; ct++) acc[ct] = (f32x4){0.f, 0.f, 0.f, 0.f};

        #pragma unroll
        for (int ks = 0; ks < 4; ks++) {
            int k0 = ks * 32 + kseg * 8;
            f16x8 af = *(const f16x8*)&atile[arow * ATS + k0];
            #pragma unroll
            for (int ct = 0; ct < 8; ct++) {
                f16x8 bf = *(const f16x8*)&wtile[(ct * 16 + l15) * WTS + k0];
                acc[ct] = __builtin_amdgcn_mfma_f32_16x16x32_f16(af, bf, acc[ct], 0, 0, 0);
            }
        }
        __syncthreads();

        #pragma unroll
        for (int rg = 0; rg < 4; rg++) {
            int m = wv * 16 + kseg * 4 + rg;
            float fc = fac[m];
            #pragma unroll
            for (int ct = 0; ct < 8; ct++) {
                atile[m * ATS + ct * 16 + l15] = (f16)(acc[ct][rg] * fc);
            }
        }
        __syncthreads();

        #pragma unroll
        for (int i = 0; i < 4; i++) {
            int flat4 = tid + i * 256;
            int rr2 = flat4 >> 4, off = (flat4 & 15) * 8;
            if (r0 + rr2 < N) {
                uint4 u = *(const uint4*)&atile[rr2 * ATS + off];
                *(uint4*)((char*)hh + ((size_t)(r0 + rr2)) * 256 + off * 2) = u;
            }
        }
        return;
    }

    if (bid < nGemm + NCONV) {
        int gtid = (bid - nGemm) * 256 + tid;
        for (int i = gtid; i < relsN4; i += NCONV * 256) {
            float4 x = ((const float4*)rels)[i];
            uint2 u;
            u.x = bc_u32(__float22half2_rn(make_float2(x.x, x.y)));
            u.y = bc_u32(__float22half2_rn(make_float2(x.z, x.w)));
            ((uint2*)rels_h)[i] = u;
        }
        return;
    }

    // ---- partition pass ----
    int pid = bid - nGemm - NCONV;
    int pair = (pid >= nChunk) ? 1 : 0;
    int chunk = pair ? pid - nChunk : pid;
    int* hist = (int*)smem;
    int* dlt  = hist + NPART;
    int* sc   = dlt + NPART;
    int* st   = sc + 256;
    const int* rsrc = pair ? rr : er;
    const int* psrc = pair ? rv : ec;
    int* part = pair ? part_r : part_e;
    int* cur  = cursors + pair * NPART;
    int e0 = chunk * CHUNK;
    int n = min(CHUNK, E - e0);

    for (int i = tid; i < NPART; i += 256) hist[i] = 0;
    __syncthreads();

    int myr[16], rk[16];
    #pragma unroll
    for (int i = 0; i < 16; i++) {
        int e = e0 + tid + i * 256;
        if (e < E) {
            int r = rsrc[e];
            myr[i] = r;
            rk[i] = atomicAdd(&hist[r >> PSHIFT], 1);
        } else myr[i] = -1;
    }
    __syncthreads();

    int h0 = (2 * tid < NPART) ? hist[2 * tid] : 0;
    int h1 = (2 * tid + 1 < NPART) ? hist[2 * tid + 1] : 0;
    int s = h0 + h1;
    sc[tid] = s;
    __syncthreads();
    for (int off = 1; off < 256; off <<= 1) {
        int v = (tid >= off) ? sc[tid - off] : 0;
        __syncthreads();
        sc[tid] += v;
        __syncthreads();
    }
    int excl = sc[tid] - s;
    if (2 * tid < NPART) dlt[2 * tid] = excl;
    if (2 * tid + 1 < NPART) dlt[2 * tid + 1] = excl + h0;
    __syncthreads();

    #pragma unroll
    for (int i = 0; i < 16; i++) {
        if (myr[i] >= 0) {
            int e = e0 + tid + i * 256;
            unsigned int pk = ((unsigned int)myr[i] << 16) | (unsigned int)(psrc[e] & 0xFFFF);
            st[dlt[myr[i] >> PSHIFT] + rk[i]] = (int)pk;
        }
    }
    __syncthreads();

    for (int p = tid; p < NPART; p += 256) {
        int len = hist[p];
        if (len > 0) {
            int g = atomicAdd(&cur[p], len);
            if (g + len > PCAP) g = PCAP - len;
            if (g < 0) g = 0;
            dlt[p] = p * PCAP + g - dlt[p];
        }
    }
    __syncthreads();

    for (int i = tid; i < n; i += 256) {
        unsigned int v = (unsigned int)st[i];
        int p = (int)(v >> 16) >> PSHIFT;
        part[dlt[p] + i] = (int)v;
    }
}

// ---------------- K2: bucket build + degree-sorted row permutation ----------------
__global__ __launch_bounds__(256) void k_bucket(
    const int* __restrict__ part_e, const int* __restrict__ part_r,
    const int* __restrict__ cursors,
    unsigned short* __restrict__ pay_e, unsigned short* __restrict__ pay_r,
    int* __restrict__ cnt, int* __restrict__ perm, int N) {
    __shared__ int bcnt[128];
    __shared__ int keys[128];
    __shared__ unsigned short bb[128 * CAP];
    int tid = threadIdx.x;
    int p = blockIdx.x;
    int pair = blockIdx.y;
    const int* part = (pair ? part_r : part_e) + (size_t)p * PCAP;
    unsigned short* pay = pair ? pay_r : pay_e;
    int* cnt_out = cnt + (size_t)pair * N;
    int n = min(cursors[pair * NPART + p], PCAP);

    if (tid < 128) bcnt[tid] = 0;
    __syncthreads();

    for (int i = tid; i < n; i += 256) {
        unsigned int v = (unsigned int)part[i];
        int rl = (int)((v >> 16) & 127);
        int slot = atomicAdd(&bcnt[rl], 1);
        if (slot < CAP) bb[rl * CAP + slot] = (unsigned short)(v & 0xFFFF);
    }
    __syncthreads();

    int rbase = p * 128;
    uint4* gdst = (uint4*)(pay + (size_t)rbase * CAP);
    const uint4* gsrc = (const uint4*)bb;
    for (int i = tid; i < 768; i += 256) gdst[i] = gsrc[i];
    if (tid < 128 && rbase + tid < N) cnt_out[rbase + tid] = bcnt[tid];

    // ---- degree-sorted permutation (att degrees; pair 0 only) ----
    if (pair == 0) {
        int nrows = min(128, N - rbase);
        if (nrows > 0) {
            if (tid < 128) keys[tid] = bcnt[tid] * 128 + tid;   // unique keys
            __syncthreads();
            if (tid < nrows) {
                int mykey = keys[tid];
                int rank = 0;
                for (int j = 0; j < nrows; j++) rank += (keys[j] < mykey) ? 1 : 0;
                perm[rbase + rank] = rbase + tid;
            }
        }
    }
}

// ---------------- K3: per-row attention + epilogue — 16-lane group owns one row,
//   4 gathers in flight; rows processed in degree-sorted order (md ~= deg) ----------------
__global__ __launch_bounds__(256) void k_row(
    const __half* __restrict__ hh, const __half* __restrict__ rels_h,
    const float* __restrict__ bws, const float* __restrict__ nrn,
    const int* __restrict__ cnt, const unsigned short* __restrict__ pay_e,
    const unsigned short* __restrict__ pay_r, const int* __restrict__ perm,
    float* __restrict__ out, int N) {
    int wv = threadIdx.x >> 6, lane = threadIdx.x & 63;
    int sub = lane >> 4, sl = lane & 15;
    int gb = lane & 48;
    int g = blockIdx.x * 16 + wv * 4 + sub;
    bool valid = g < N;
    int r = valid ? perm[g] : 0;          // degree-sorted row id (< N)

    const char* hB = (const char*)hh + sl * 16;
    const char* rB = (const char*)rels_h + sl * 16;
    uint4 hraw = *(const uint4*)(hB + ((size_t)r << 8));
    float nrn_v = nrn[r];

    int deg  = valid ? min(cnt[r], CAP) : 0;
    int degr = valid ? min(cnt[N + r], CAP) : 0;

    size_t be = (size_t)r * CAP;
    int i0e = (sl      < deg) ? (int)pay_e[be + sl]      : 0;
    int i1e = (sl + 16 < deg) ? (int)pay_e[be + sl + 16] : 0;
    int i2e = (sl + 32 < deg) ? (int)pay_e[be + sl + 32] : 0;
    int i0r = (sl      < degr) ? (int)pay_r[be + sl]      : 0;
    int i1r = (sl + 16 < degr) ? (int)pay_r[be + sl + 16] : 0;
    int i2r = (sl + 32 < degr) ? (int)pay_r[be + sl + 32] : 0;

    int md = deg;
    md = max(md, __shfl_xor(md, 16, 64));
    md = max(md, __shfl_xor(md, 32, 64));
    int mdr = degr;
    mdr = max(mdr, __shfl_xor(mdr, 16, 64));
    mdr = max(mdr, __shfl_xor(mdr, 32, 64));

    __half2 aA[4] = {bc_h2(0u), bc_h2(0u), bc_h2(0u), bc_h2(0u)};
    float den = 0.f;

    // 4 edges per round, per-edge weight masks; 4 independent gathers in flight
    auto att4 = [&](int idxreg, int base) {
        #pragma unroll
        for (int k = 0; k < 16; k += 4) {
            int t = base + k;
            if (t >= md) break;
            int c0 = __shfl(idxreg, gb | k);
            int c1 = __shfl(idxreg, gb | (k + 1));
            int c2 = __shfl(idxreg, gb | (k + 2));
            int c3 = __shfl(idxreg, gb | (k + 3));
            uint4 v0 = *(const uint4*)(hB + ((size_t)c0 << 8));
            uint4 v1 = *(const uint4*)(hB + ((size_t)c1 << 8));
            uint4 v2 = *(const uint4*)(hB + ((size_t)c2 << 8));
            uint4 v3 = *(const uint4*)(hB + ((size_t)c3 << 8));
            float s0 = dot8d(hraw, v0);
            float s1 = dot8d(hraw, v1);
            float s2 = dot8d(hraw, v2);
            float s3 = dot8d(hraw, v3);
            gred4(s0, s1, s2, s3);
            float w0 = (t     < deg) ? __expf(s0) : 0.f;
            float w1 = (t + 1 < deg) ? __expf(s1) : 0.f;
            float w2 = (t + 2 < deg) ? __expf(s2) : 0.f;
            float w3 = (t + 3 < deg) ? __expf(s3) : 0.f;
            den += (w0 + w1) + (w2 + w3);
            acc8h(aA, w0, v0);
            acc8h(aA, w1, v1);
            acc8h(aA, w2, v2);
            acc8h(aA, w3, v3);
        }
    };
    att4(i0e, 0);
    if (md > 16) att4(i1e, 16);
    if (md > 32) att4(i2e, 32);

    __half2 rA[4] = {bc_h2(0u), bc_h2(0u), bc_h2(0u), bc_h2(0u)};
    auto rel4 = [&](int idxreg, int base) {
        #pragma unroll
        for (int k = 0; k < 16; k += 4) {
            int t = base + k;
            if (t >= mdr) break;
            int c0 = __shfl(idxreg, gb | k);
            int c1 = __shfl(idxreg, gb | (k + 1));
            int c2 = __shfl(idxreg, gb | (k + 2));
            int c3 = __shfl(idxreg, gb | (k + 3));
            uint4 v0 = *(const uint4*)(rB + ((size_t)c0 << 8));
            uint4 v1 = *(const uint4*)(rB + ((size_t)c1 << 8));
            uint4 v2 = *(const uint4*)(rB + ((size_t)c2 << 8));
            uint4 v3 = *(const uint4*)(rB + ((size_t)c3 << 8));
            if (t     < degr) add8h(rA, v0);
            if (t + 1 < degr) add8h(rA, v1);
            if (t + 2 < degr) add8h(rA, v2);
            if (t + 3 < degr) add8h(rA, v3);
        }
    };
    rel4(i0r, 0);
    if (mdr > 16) rel4(i1r, 16);
    if (mdr > 32) rel4(i2r, 32);

    // ---- epilogue (per-group; gred = intra-16 = this row's 128 dims) ----
    float inv  = 1.f / fmaxf(den, EPS);
    float innr = 0.1f / nrn_v;
    float2 a0 = __half22float2(aA[0]), a1 = __half22float2(aA[1]);
    float2 a2 = __half22float2(aA[2]), a3 = __half22float2(aA[3]);
    float2 r0f = __half22float2(rA[0]), r1f = __half22float2(rA[1]);
    float2 r2f = __half22float2(rA[2]), r3f = __half22float2(rA[3]);
    float v0 = a0.x * inv + r0f.x * innr, v1 = a0.y * inv + r0f.y * innr;
    float v2_ = a1.x * inv + r1f.x * innr, v3 = a1.y * inv + r1f.y * innr;
    float v4 = a2.x * inv + r2f.x * innr, v5 = a2.y * inv + r2f.y * innr;
    float v6 = a3.x * inv + r3f.x * innr, v7 = a3.y * inv + r3f.y * innr;

    float pn = v0*v0 + v1*v1 + v2_*v2_ + v3*v3 + v4*v4 + v5*v5 + v6*v6 + v7*v7;
    pn = gred(pn);
    float sq = sqrtf(pn);
    float nn = fmaxf(sq, EPS);
    float tt = __expf(2.f * fminf(nn, 15.f));
    float g2 = (tt - 1.f) / ((tt + 1.f) * nn);
    float n2 = fmaxf(g2 * sq, EPS);
    float pf = fminf(1.f, MAXNORM / n2);
    float gp = g2 * pf;
    float o0 = gp*v0, o1 = gp*v1, o2 = gp*v2_, o3 = gp*v3;
    float o4 = gp*v4, o5 = gp*v5, o6 = gp*v6, o7 = gp*v7;
    float un = n2 * pf;
    float u2 = un * un;

    const float4* bp = (const float4*)(bws + sl * 8);
    float4 b0 = bp[0], b1 = bp[1];
    float bv2 = bws[128];
    float puv = o0*b0.x + o1*b0.y + o2*b0.z + o3*b0.w
              + o4*b1.x + o5*b1.y + o6*b1.z + o7*b1.w;
    puv = gred(puv);
    float ca = 1.f + 2.f * puv + bv2;
    float cb = 1.f - u2;
    float idm = 1.f / fmaxf(1.f + 2.f * puv + u2 * bv2, EPS);
    float x0 = (ca*o0 + cb*b0.x) * idm, x1 = (ca*o1 + cb*b0.y) * idm;
    float x2 = (ca*o2 + cb*b0.z) * idm, x3 = (ca*o3 + cb*b0.w) * idm;
    float x4 = (ca*o4 + cb*b1.x) * idm, x5 = (ca*o5 + cb*b1.y) * idm;
    float x6 = (ca*o6 + cb*b1.z) * idm, x7 = (ca*o7 + cb*b1.w) * idm;
    float pr = x0*x0 + x1*x1 + x2*x2 + x3*x3 + x4*x4 + x5*x5 + x6*x6 + x7*x7;
    pr = gred(pr);
    float n3 = fmaxf(sqrtf(pr), EPS);
    float pf3 = fminf(1.f, MAXNORM / n3);

    if (valid) {
        float4* op = (float4*)(out + (size_t)r * D_DIM + sl * 8);
        op[0] = make_float4(x0 * pf3, x1 * pf3, x2 * pf3, x3 * pf3);
        op[1] = make_float4(x4 * pf3, x5 * pf3, x6 * pf3, x7 * pf3);
    }
}

// ---------------- launch ----------------
extern "C" void kernel_launch(void* const* d_in, const int* in_sizes, int n_in,
                              void* d_out, int out_size, void* d_ws, size_t ws_size,
                              hipStream_t stream) {
    const float* ents = (const float*)d_in[0];
    const float* rels = (const float*)d_in[1];
    const float* W    = (const float*)d_in[2];
    const float* bias = (const float*)d_in[3];
    const int* er = (const int*)d_in[4];
    const int* ec = (const int*)d_in[5];
    const int* rr = (const int*)d_in[6];
    const int* rv = (const int*)d_in[7];
    const float* nrn = (const float*)d_in[8];
    int N = in_sizes[0] / D_DIM;
    int R = in_sizes[1] / D_DIM;
    int E = in_sizes[4];
    float* out = (float*)d_out;

    char* p = (char*)d_ws;
    auto alloc = [&](size_t bytes) {
        char* q = p;
        p += (bytes + 255) & ~(size_t)255;
        return q;
    };
    const int PADN = NPART * 128;
    __half* hh     = (__half*)alloc((size_t)N * D_DIM * 2);
    f16* rels_h    = (f16*)alloc((size_t)R * D_DIM * 2);
    f16* Wt_h      = (f16*)alloc((size_t)D_DIM * D_DIM * 2);
    int* cnt    = (int*)alloc((size_t)2 * N * 4);
    unsigned short* pay_e = (unsigned short*)alloc((size_t)PADN * CAP * 2);
    unsigned short* pay_r = (unsigned short*)alloc((size_t)PADN * CAP * 2);
    int* part_e = (int*)alloc((size_t)NPART * PCAP * 4);
    int* part_r = (int*)alloc((size_t)NPART * PCAP * 4);
    int* cursors = (int*)alloc((size_t)2 * NPART * 4);
    int* perm    = (int*)alloc((size_t)N * 4);
    float* bws   = (float*)alloc((size_t)132 * 4);

    int nGemm = (N + 63) / 64;
    int nChunk = (E + CHUNK - 1) / CHUNK;
    int relsN4 = R * D_DIM / 4;

    k_pre0<<<2, 256, 0, stream>>>(W, Wt_h, bias, bws, cursors);

    k_main<<<nGemm + NCONV + 2 * nChunk, 256, 0, stream>>>(
        ents, Wt_h, hh, er, ec, rr, rv, part_e, part_r, cursors,
        rels, rels_h, relsN4, N, E, nGemm, nChunk);

    k_bucket<<<dim3(NPART, 2), 256, 0, stream>>>(part_e, part_r, cursors,
                                                 pay_e, pay_r, cnt, perm, N);

    k_row<<<(N + 15) / 16, 256, 0, stream>>>(
        hh, (const __half*)rels_h, bws, nrn, cnt, pay_e, pay_r, perm, out, N);
}

// Round 20
// 74.304 us; speedup vs baseline: 1.0686x; 1.0686x over previous
//
#include <hip/hip_runtime.h>
#include <hip/hip_fp16.h>
#include <math.h>

#define EPS 1e-7f
#define PROJ_EPS 1e-5f
#define MAXNORM (1.0f - PROJ_EPS)
#define D_DIM 128
#define CAP 48          // bucket capacity; deg ~ Binom(640k,1/50k), P(deg>48) ~ 1e-20
#define PSHIFT 7        // partition = row >> 7  (128 rows/partition)
#define NPART 392       // 50000>>7 = 390 max -> 391 used, pad to 392
#define PCAP 2048       // edges per partition: mean 1638, sigma 40 -> 10 sigma margin
#define CHUNK 4096      // edges per part block
#define NCONV 32        // blocks converting rels fp32 -> fp16
#define ATS 136         // atile k-stride (halfs)
#define WTS 136         // wtile k-stride (halfs)
#define PRE0_SMEM (64 * 132 * 4)
#define MAIN_SMEM (64 * ATS * 2 + 128 * WTS * 2 + 256)   // 52.5 KB: gemm arena >= part arena

typedef _Float16 f16;
typedef __attribute__((ext_vector_type(4))) _Float16 f16x4;
typedef __attribute__((ext_vector_type(8))) _Float16 f16x8;
typedef __attribute__((ext_vector_type(4))) float f32x4;

// ---------------- helpers ----------------
__device__ inline float wred(float v) {
    #pragma unroll
    for (int o = 32; o; o >>= 1) v += __shfl_xor(v, o, 64);
    return v;
}
__device__ inline float gred(float v) {
    v += __shfl_xor(v, 1, 64);
    v += __shfl_xor(v, 2, 64);
    v += __shfl_xor(v, 4, 64);
    v += __shfl_xor(v, 8, 64);
    return v;
}
__device__ inline void gred4(float& a, float& b, float& c, float& d) {
    a += __shfl_xor(a, 1, 64);  b += __shfl_xor(b, 1, 64);
    c += __shfl_xor(c, 1, 64);  d += __shfl_xor(d, 1, 64);
    a += __shfl_xor(a, 2, 64);  b += __shfl_xor(b, 2, 64);
    c += __shfl_xor(c, 2, 64);  d += __shfl_xor(d, 2, 64);
    a += __shfl_xor(a, 4, 64);  b += __shfl_xor(b, 4, 64);
    c += __shfl_xor(c, 4, 64);  d += __shfl_xor(d, 4, 64);
    a += __shfl_xor(a, 8, 64);  b += __shfl_xor(b, 8, 64);
    c += __shfl_xor(c, 8, 64);  d += __shfl_xor(d, 8, 64);
}
__device__ inline __half2 bc_h2(unsigned int u) { return *(__half2*)&u; }
__device__ inline unsigned int bc_u32(__half2 h) { return *(unsigned int*)&h; }

typedef _Float16 h2v __attribute__((ext_vector_type(2)));
__device__ inline h2v as_h2v(unsigned int u) { union { unsigned int u; h2v h; } c; c.u = u; return c.h; }

__device__ inline float dot8d(uint4 a, uint4 v) {
#if __has_builtin(__builtin_amdgcn_fdot2)
    float s = __builtin_amdgcn_fdot2(as_h2v(a.x), as_h2v(v.x), 0.f, false);
    s = __builtin_amdgcn_fdot2(as_h2v(a.y), as_h2v(v.y), s, false);
    s = __builtin_amdgcn_fdot2(as_h2v(a.z), as_h2v(v.z), s, false);
    s = __builtin_amdgcn_fdot2(as_h2v(a.w), as_h2v(v.w), s, false);
    return s;
#else
    __half2 t = __hmul2(bc_h2(a.x), bc_h2(v.x));
    t = __hfma2(bc_h2(a.y), bc_h2(v.y), t);
    t = __hfma2(bc_h2(a.z), bc_h2(v.z), t);
    t = __hfma2(bc_h2(a.w), bc_h2(v.w), t);
    return __low2float(t) + __high2float(t);
#endif
}
__device__ inline void acc8h(__half2* A, float w, uint4 v) {
    __half2 w2 = __float2half2_rn(w);
    A[0] = __hfma2(w2, bc_h2(v.x), A[0]);
    A[1] = __hfma2(w2, bc_h2(v.y), A[1]);
    A[2] = __hfma2(w2, bc_h2(v.z), A[2]);
    A[3] = __hfma2(w2, bc_h2(v.w), A[3]);
}
__device__ inline void add8h(__half2* A, uint4 v) {
    A[0] = __hadd2(A[0], bc_h2(v.x));
    A[1] = __hadd2(A[1], bc_h2(v.y));
    A[2] = __hadd2(A[2], bc_h2(v.z));
    A[3] = __hadd2(A[3], bc_h2(v.w));
}

// ---------------- K0: k_pre0 = {bias + cursors-zero | W-transpose->fp16} ----------------
__global__ __launch_bounds__(256) void k_pre0(
    const float* __restrict__ W, f16* __restrict__ Wt_h,
    const float* __restrict__ bias, float* __restrict__ bws,
    int* __restrict__ cursors) {
    __shared__ alignas(16) unsigned char smem[PRE0_SMEM];
    int tid = threadIdx.x;

    if (blockIdx.x == 0) {
        for (int i = tid; i < 2 * NPART; i += 256) cursors[i] = 0;
        if (tid < 64) {
            int l = tid;
            float2 bv = ((const float2*)bias)[l];
            float bn = fmaxf(sqrtf(wred(bv.x * bv.x + bv.y * bv.y)), EPS);
            float gb = tanhf(fminf(bn, 15.f)) / bn;
            float bx = gb * bv.x, by = gb * bv.y;
            float nb = fmaxf(sqrtf(wred(bx * bx + by * by)), EPS);
            float pb = fminf(1.f, MAXNORM / nb);
            bx *= pb; by *= pb;
            ((float2*)bws)[l] = make_float2(bx, by);
            float v2 = wred(bx * bx + by * by);
            if (l == 0) bws[128] = v2;
        }
        return;
    }

    // ---- W [k][c] fp32 -> Wt_h [c][k] fp16 (two 64-row passes through LDS) ----
    float* lts = (float*)smem;          // [64][132]
    unsigned int* wt_u = (unsigned int*)Wt_h;
    for (int pass = 0; pass < 2; pass++) {
        #pragma unroll
        for (int i = 0; i < 8; i++) {
            int flat = (tid + i * 256) * 4;
            int kr = flat >> 7, cc = flat & 127;
            float4 x = *(const float4*)(W + (size_t)(pass * 64 + kr) * D_DIM + cc);
            *(float4*)&lts[kr * 132 + cc] = x;
        }
        __syncthreads();
        #pragma unroll
        for (int i = 0; i < 16; i++) {
            int flat2 = tid + i * 256;
            int c = flat2 >> 5, kp = flat2 & 31;
            float lo = lts[(2 * kp) * 132 + c];
            float hi = lts[(2 * kp + 1) * 132 + c];
            wt_u[c * 64 + pass * 32 + kp] = bc_u32(__float22half2_rn(make_float2(lo, hi)));
        }
        __syncthreads();
    }
}

// ---------------- K1: k_main = {MFMA logmap-GEMM | rels->fp16 | partition} ----------------
__global__ __launch_bounds__(256) void k_main(
    const float* __restrict__ ents, const f16* __restrict__ Wt_h,
    __half* __restrict__ hh,
    const int* __restrict__ er, const int* __restrict__ ec,
    const int* __restrict__ rr, const int* __restrict__ rv,
    int* __restrict__ part_e, int* __restrict__ part_r,
    int* __restrict__ cursors,
    const float* __restrict__ rels, f16* __restrict__ rels_h, int relsN4,
    int N, int E, int nGemm, int nChunk) {
    __shared__ alignas(16) unsigned char smem[MAIN_SMEM];
    int tid = threadIdx.x;
    int bid = blockIdx.x;

    if (bid < nGemm) {
        f16* atile = (f16*)smem;
        f16* wtile = (f16*)(smem + 64 * ATS * 2);
        float* fac = (float*)(smem + 64 * ATS * 2 + 128 * WTS * 2);
        int lane = tid & 63;
        int wv = tid >> 6;
        int r0 = bid * 64;

        #pragma unroll
        for (int i = 0; i < 8; i++) {
            int flat = (tid + i * 256) * 4;
            int rr2 = flat >> 7, cc = flat & 127;
            float4 x = make_float4(0.f, 0.f, 0.f, 0.f);
            if (r0 + rr2 < N) x = *(const float4*)(ents + (size_t)(r0 + rr2) * D_DIM + cc);
            f16x4 v4 = {(f16)x.x, (f16)x.y, (f16)x.z, (f16)x.w};
            *(f16x4*)&atile[rr2 * ATS + cc] = v4;
            float s = x.x * x.x + x.y * x.y + x.z * x.z + x.w * x.w;
            s += __shfl_xor(s, 1, 64);
            s += __shfl_xor(s, 2, 64);
            s += __shfl_xor(s, 4, 64);
            s += __shfl_xor(s, 8, 64);
            s += __shfl_xor(s, 16, 64);
            if ((lane & 31) == 0) fac[rr2] = s;
        }
        #pragma unroll
        for (int i = 0; i < 8; i++) {
            int flat4 = tid + i * 256;
            int c = flat4 >> 4, off = (flat4 & 15) * 8;
            uint4 u = ((const uint4*)Wt_h)[flat4];
            *(uint4*)&wtile[c * WTS + off] = u;
        }
        __syncthreads();

        if (tid < 64) {
            float n = sqrtf(fac[tid]);
            float ncl = fminf(fmaxf(n, EPS), MAXNORM);
            float at = 0.5f * logf((1.f + ncl) / (1.f - ncl));
            fac[tid] = at / fmaxf(n, EPS);
        }
        __syncthreads();

        int l15 = lane & 15, kseg = lane >> 4;
        int arow = wv * 16 + l15;

        f32x4 acc[8];
        #pragma unroll
        for (int ct = 0; ct < 8; ct++) acc[ct] = (f32x4){0.f, 0.f, 0.f, 0.f};

        #pragma unroll
        for (int ks = 0; ks < 4; ks++) {
            int k0 = ks * 32 + kseg * 8;
            f16x8 af = *(const f16x8*)&atile[arow * ATS + k0];
            #pragma unroll
            for (int ct = 0; ct < 8; ct++) {
                f16x8 bf = *(const f16x8*)&wtile[(ct * 16 + l15) * WTS + k0];
                acc[ct] = __builtin_amdgcn_mfma_f32_16x16x32_f16(af, bf, acc[ct], 0, 0, 0);
            }
        }
        __syncthreads();

        #pragma unroll
        for (int rg = 0; rg < 4; rg++) {
            int m = wv * 16 + kseg * 4 + rg;
            float fc = fac[m];
            #pragma unroll
            for (int ct = 0; ct < 8; ct++) {
                atile[m * ATS + ct * 16 + l15] = (f16)(acc[ct][rg] * fc);
            }
        }
        __syncthreads();

        #pragma unroll
        for (int i = 0; i < 4; i++) {
            int flat4 = tid + i * 256;
            int rr2 = flat4 >> 4, off = (flat4 & 15) * 8;
            if (r0 + rr2 < N) {
                uint4 u = *(const uint4*)&atile[rr2 * ATS + off];
                *(uint4*)((char*)hh + ((size_t)(r0 + rr2)) * 256 + off * 2) = u;
            }
        }
        return;
    }

    if (bid < nGemm + NCONV) {
        int gtid = (bid - nGemm) * 256 + tid;
        for (int i = gtid; i < relsN4; i += NCONV * 256) {
            float4 x = ((const float4*)rels)[i];
            uint2 u;
            u.x = bc_u32(__float22half2_rn(make_float2(x.x, x.y)));
            u.y = bc_u32(__float22half2_rn(make_float2(x.z, x.w)));
            ((uint2*)rels_h)[i] = u;
        }
        return;
    }

    // ---- partition pass ----
    int pid = bid - nGemm - NCONV;
    int pair = (pid >= nChunk) ? 1 : 0;
    int chunk = pair ? pid - nChunk : pid;
    int* hist = (int*)smem;
    int* dlt  = hist + NPART;
    int* sc   = dlt + NPART;
    int* st   = sc + 256;
    const int* rsrc = pair ? rr : er;
    const int* psrc = pair ? rv : ec;
    int* part = pair ? part_r : part_e;
    int* cur  = cursors + pair * NPART;
    int e0 = chunk * CHUNK;
    int n = min(CHUNK, E - e0);

    for (int i = tid; i < NPART; i += 256) hist[i] = 0;
    __syncthreads();

    int myr[16], rk[16];
    #pragma unroll
    for (int i = 0; i < 16; i++) {
        int e = e0 + tid + i * 256;
        if (e < E) {
            int r = rsrc[e];
            myr[i] = r;
            rk[i] = atomicAdd(&hist[r >> PSHIFT], 1);
        } else myr[i] = -1;
    }
    __syncthreads();

    int h0 = (2 * tid < NPART) ? hist[2 * tid] : 0;
    int h1 = (2 * tid + 1 < NPART) ? hist[2 * tid + 1] : 0;
    int s = h0 + h1;
    sc[tid] = s;
    __syncthreads();
    for (int off = 1; off < 256; off <<= 1) {
        int v = (tid >= off) ? sc[tid - off] : 0;
        __syncthreads();
        sc[tid] += v;
        __syncthreads();
    }
    int excl = sc[tid] - s;
    if (2 * tid < NPART) dlt[2 * tid] = excl;
    if (2 * tid + 1 < NPART) dlt[2 * tid + 1] = excl + h0;
    __syncthreads();

    #pragma unroll
    for (int i = 0; i < 16; i++) {
        if (myr[i] >= 0) {
            int e = e0 + tid + i * 256;
            unsigned int pk = ((unsigned int)myr[i] << 16) | (unsigned int)(psrc[e] & 0xFFFF);
            st[dlt[myr[i] >> PSHIFT] + rk[i]] = (int)pk;
        }
    }
    __syncthreads();

    for (int p = tid; p < NPART; p += 256) {
        int len = hist[p];
        if (len > 0) {
            int g = atomicAdd(&cur[p], len);
            if (g + len > PCAP) g = PCAP - len;
            if (g < 0) g = 0;
            dlt[p] = p * PCAP + g - dlt[p];
        }
    }
    __syncthreads();

    for (int i = tid; i < n; i += 256) {
        unsigned int v = (unsigned int)st[i];
        int p = (int)(v >> 16) >> PSHIFT;
        part[dlt[p] + i] = (int)v;
    }
}

// ---------------- K2: bucket build ----------------
__global__ __launch_bounds__(256) void k_bucket(
    const int* __restrict__ part_e, const int* __restrict__ part_r,
    const int* __restrict__ cursors,
    unsigned short* __restrict__ pay_e, unsigned short* __restrict__ pay_r,
    int* __restrict__ cnt, int N) {
    __shared__ int bcnt[128];
    __shared__ unsigned short bb[128 * CAP];
    int tid = threadIdx.x;
    int p = blockIdx.x;
    int pair = blockIdx.y;
    const int* part = (pair ? part_r : part_e) + (size_t)p * PCAP;
    unsigned short* pay = pair ? pay_r : pay_e;
    int* cnt_out = cnt + (size_t)pair * N;
    int n = min(cursors[pair * NPART + p], PCAP);

    if (tid < 128) bcnt[tid] = 0;
    __syncthreads();

    for (int i = tid; i < n; i += 256) {
        unsigned int v = (unsigned int)part[i];
        int rl = (int)((v >> 16) & 127);
        int slot = atomicAdd(&bcnt[rl], 1);
        if (slot < CAP) bb[rl * CAP + slot] = (unsigned short)(v & 0xFFFF);
    }
    __syncthreads();

    int rbase = p * 128;
    uint4* gdst = (uint4*)(pay + (size_t)rbase * CAP);
    const uint4* gsrc = (const uint4*)bb;
    for (int i = tid; i < 768; i += 256) gdst[i] = gsrc[i];
    if (tid < 128 && rbase + tid < N) cnt_out[rbase + tid] = bcnt[tid];
}

// ---------------- K3: per-row attention + epilogue — 16-lane group owns one row,
//                  4 gathers in flight ----------------
__global__ __launch_bounds__(256) void k_row(
    const __half* __restrict__ hh, const __half* __restrict__ rels_h,
    const float* __restrict__ bws, const float* __restrict__ nrn,
    const int* __restrict__ cnt, const unsigned short* __restrict__ pay_e,
    const unsigned short* __restrict__ pay_r,
    float* __restrict__ out, int N) {
    int wv = threadIdx.x >> 6, lane = threadIdx.x & 63;
    int sub = lane >> 4, sl = lane & 15;
    int gb = lane & 48;
    int r = blockIdx.x * 16 + wv * 4 + sub;
    bool valid = r < N;
    int rc = valid ? r : 0;

    const char* hB = (const char*)hh + sl * 16;
    const char* rB = (const char*)rels_h + sl * 16;
    uint4 hraw = *(const uint4*)(hB + ((size_t)rc << 8));
    float nrn_v = nrn[rc];

    int deg  = valid ? min(cnt[rc], CAP) : 0;
    int degr = valid ? min(cnt[N + rc], CAP) : 0;

    size_t be = (size_t)rc * CAP;
    int i0e = (sl      < deg) ? (int)pay_e[be + sl]      : 0;
    int i1e = (sl + 16 < deg) ? (int)pay_e[be + sl + 16] : 0;
    int i2e = (sl + 32 < deg) ? (int)pay_e[be + sl + 32] : 0;
    int i0r = (sl      < degr) ? (int)pay_r[be + sl]      : 0;
    int i1r = (sl + 16 < degr) ? (int)pay_r[be + sl + 16] : 0;
    int i2r = (sl + 32 < degr) ? (int)pay_r[be + sl + 32] : 0;

    int md = deg;
    md = max(md, __shfl_xor(md, 16, 64));
    md = max(md, __shfl_xor(md, 32, 64));
    int mdr = degr;
    mdr = max(mdr, __shfl_xor(mdr, 16, 64));
    mdr = max(mdr, __shfl_xor(mdr, 32, 64));

    __half2 aA[4] = {bc_h2(0u), bc_h2(0u), bc_h2(0u), bc_h2(0u)};
    float den = 0.f;

    // 4 edges per round, per-edge masks; 4 independent gathers in flight
    auto att4 = [&](int idxreg, int base) {
        #pragma unroll
        for (int k = 0; k < 16; k += 4) {
            int t = base + k;
            if (t >= md) break;
            int c0 = __shfl(idxreg, gb | k);
            int c1 = __shfl(idxreg, gb | (k + 1));
            int c2 = __shfl(idxreg, gb | (k + 2));
            int c3 = __shfl(idxreg, gb | (k + 3));
            uint4 v0 = *(const uint4*)(hB + ((size_t)c0 << 8));
            uint4 v1 = *(const uint4*)(hB + ((size_t)c1 << 8));
            uint4 v2 = *(const uint4*)(hB + ((size_t)c2 << 8));
            uint4 v3 = *(const uint4*)(hB + ((size_t)c3 << 8));
            float s0 = dot8d(hraw, v0);
            float s1 = dot8d(hraw, v1);
            float s2 = dot8d(hraw, v2);
            float s3 = dot8d(hraw, v3);
            gred4(s0, s1, s2, s3);
            float w0 = (t     < deg) ? __expf(s0) : 0.f;
            float w1 = (t + 1 < deg) ? __expf(s1) : 0.f;
            float w2 = (t + 2 < deg) ? __expf(s2) : 0.f;
            float w3 = (t + 3 < deg) ? __expf(s3) : 0.f;
            den += (w0 + w1) + (w2 + w3);
            acc8h(aA, w0, v0);
            acc8h(aA, w1, v1);
            acc8h(aA, w2, v2);
            acc8h(aA, w3, v3);
        }
    };
    att4(i0e, 0);
    if (md > 16) att4(i1e, 16);
    if (md > 32) att4(i2e, 32);

    __half2 rA[4] = {bc_h2(0u), bc_h2(0u), bc_h2(0u), bc_h2(0u)};
    auto rel4 = [&](int idxreg, int base) {
        #pragma unroll
        for (int k = 0; k < 16; k += 4) {
            int t = base + k;
            if (t >= mdr) break;
            int c0 = __shfl(idxreg, gb | k);
            int c1 = __shfl(idxreg, gb | (k + 1));
            int c2 = __shfl(idxreg, gb | (k + 2));
            int c3 = __shfl(idxreg, gb | (k + 3));
            uint4 v0 = *(const uint4*)(rB + ((size_t)c0 << 8));
            uint4 v1 = *(const uint4*)(rB + ((size_t)c1 << 8));
            uint4 v2 = *(const uint4*)(rB + ((size_t)c2 << 8));
            uint4 v3 = *(const uint4*)(rB + ((size_t)c3 << 8));
            if (t     < degr) add8h(rA, v0);
            if (t + 1 < degr) add8h(rA, v1);
            if (t + 2 < degr) add8h(rA, v2);
            if (t + 3 < degr) add8h(rA, v3);
        }
    };
    rel4(i0r, 0);
    if (mdr > 16) rel4(i1r, 16);
    if (mdr > 32) rel4(i2r, 32);

    // ---- epilogue (per-group; gred = intra-16 = this row's 128 dims) ----
    float inv  = 1.f / fmaxf(den, EPS);
    float innr = 0.1f / nrn_v;
    float2 a0 = __half22float2(aA[0]), a1 = __half22float2(aA[1]);
    float2 a2 = __half22float2(aA[2]), a3 = __half22float2(aA[3]);
    float2 r0f = __half22float2(rA[0]), r1f = __half22float2(rA[1]);
    float2 r2f = __half22float2(rA[2]), r3f = __half22float2(rA[3]);
    float v0 = a0.x * inv + r0f.x * innr, v1 = a0.y * inv + r0f.y * innr;
    float v2_ = a1.x * inv + r1f.x * innr, v3 = a1.y * inv + r1f.y * innr;
    float v4 = a2.x * inv + r2f.x * innr, v5 = a2.y * inv + r2f.y * innr;
    float v6 = a3.x * inv + r3f.x * innr, v7 = a3.y * inv + r3f.y * innr;

    float pn = v0*v0 + v1*v1 + v2_*v2_ + v3*v3 + v4*v4 + v5*v5 + v6*v6 + v7*v7;
    pn = gred(pn);
    float sq = sqrtf(pn);
    float nn = fmaxf(sq, EPS);
    float tt = __expf(2.f * fminf(nn, 15.f));
    float g = (tt - 1.f) / ((tt + 1.f) * nn);
    float n2 = fmaxf(g * sq, EPS);
    float pf = fminf(1.f, MAXNORM / n2);
    float gp = g * pf;
    float o0 = gp*v0, o1 = gp*v1, o2 = gp*v2_, o3 = gp*v3;
    float o4 = gp*v4, o5 = gp*v5, o6 = gp*v6, o7 = gp*v7;
    float un = n2 * pf;
    float u2 = un * un;

    const float4* bp = (const float4*)(bws + sl * 8);
    float4 b0 = bp[0], b1 = bp[1];
    float bv2 = bws[128];
    float puv = o0*b0.x + o1*b0.y + o2*b0.z + o3*b0.w
              + o4*b1.x + o5*b1.y + o6*b1.z + o7*b1.w;
    puv = gred(puv);
    float ca = 1.f + 2.f * puv + bv2;
    float cb = 1.f - u2;
    float idm = 1.f / fmaxf(1.f + 2.f * puv + u2 * bv2, EPS);
    float x0 = (ca*o0 + cb*b0.x) * idm, x1 = (ca*o1 + cb*b0.y) * idm;
    float x2 = (ca*o2 + cb*b0.z) * idm, x3 = (ca*o3 + cb*b0.w) * idm;
    float x4 = (ca*o4 + cb*b1.x) * idm, x5 = (ca*o5 + cb*b1.y) * idm;
    float x6 = (ca*o6 + cb*b1.z) * idm, x7 = (ca*o7 + cb*b1.w) * idm;
    float pr = x0*x0 + x1*x1 + x2*x2 + x3*x3 + x4*x4 + x5*x5 + x6*x6 + x7*x7;
    pr = gred(pr);
    float n3 = fmaxf(sqrtf(pr), EPS);
    float pf3 = fminf(1.f, MAXNORM / n3);

    if (valid) {
        float4* op = (float4*)(out + (size_t)r * D_DIM + sl * 8);
        op[0] = make_float4(x0 * pf3, x1 * pf3, x2 * pf3, x3 * pf3);
        op[1] = make_float4(x4 * pf3, x5 * pf3, x6 * pf3, x7 * pf3);
    }
}

// ---------------- launch ----------------
extern "C" void kernel_launch(void* const* d_in, const int* in_sizes, int n_in,
                              void* d_out, int out_size, void* d_ws, size_t ws_size,
                              hipStream_t stream) {
    const float* ents = (const float*)d_in[0];
    const float* rels = (const float*)d_in[1];
    const float* W    = (const float*)d_in[2];
    const float* bias = (const float*)d_in[3];
    const int* er = (const int*)d_in[4];
    const int* ec = (const int*)d_in[5];
    const int* rr = (const int*)d_in[6];
    const int* rv = (const int*)d_in[7];
    const float* nrn = (const float*)d_in[8];
    int N = in_sizes[0] / D_DIM;
    int R = in_sizes[1] / D_DIM;
    int E = in_sizes[4];
    float* out = (float*)d_out;

    char* p = (char*)d_ws;
    auto alloc = [&](size_t bytes) {
        char* q = p;
        p += (bytes + 255) & ~(size_t)255;
        return q;
    };
    const int PADN = NPART * 128;
    __half* hh     = (__half*)alloc((size_t)N * D_DIM * 2);
    f16* rels_h    = (f16*)alloc((size_t)R * D_DIM * 2);
    f16* Wt_h      = (f16*)alloc((size_t)D_DIM * D_DIM * 2);
    int* cnt    = (int*)alloc((size_t)2 * N * 4);
    unsigned short* pay_e = (unsigned short*)alloc((size_t)PADN * CAP * 2);
    unsigned short* pay_r = (unsigned short*)alloc((size_t)PADN * CAP * 2);
    int* part_e = (int*)alloc((size_t)NPART * PCAP * 4);
    int* part_r = (int*)alloc((size_t)NPART * PCAP * 4);
    int* cursors = (int*)alloc((size_t)2 * NPART * 4);
    float* bws   = (float*)alloc((size_t)132 * 4);

    int nGemm = (N + 63) / 64;
    int nChunk = (E + CHUNK - 1) / CHUNK;
    int relsN4 = R * D_DIM / 4;

    k_pre0<<<2, 256, 0, stream>>>(W, Wt_h, bias, bws, cursors);

    k_main<<<nGemm + NCONV + 2 * nChunk, 256, 0, stream>>>(
        ents, Wt_h, hh, er, ec, rr, rv, part_e, part_r, cursors,
        rels, rels_h, relsN4, N, E, nGemm, nChunk);

    k_bucket<<<dim3(NPART, 2), 256, 0, stream>>>(part_e, part_r, cursors, pay_e, pay_r, cnt, N);

    k_row<<<(N + 15) / 16, 256, 0, stream>>>(
        hh, (const __half*)rels_h, bws, nrn, cnt, pay_e, pay_r, out, N);
}